// Round 4
// baseline (13346.635 us; speedup 1.0000x reference)
//
#include <hip/hip_runtime.h>

typedef __attribute__((ext_vector_type(8))) short bf16x8;   // 8 bf16 (4 VGPRs)
typedef __attribute__((ext_vector_type(4))) float f32x4;
typedef unsigned short u16;
typedef unsigned long long u64;

#define T_SEQ 512
#define NBLK  192
#define FPAD  16        // ints per flag slot = one 64B line
#define RSLOT 4         // ring depth for h0ring / h1ring / pabuf

__device__ __forceinline__ u16 f2bf(float f) {
  unsigned int u = __float_as_uint(f);
  u += 0x7fffu + ((u >> 16) & 1u);           // RNE
  return (u16)(u >> 16);
}
__device__ __forceinline__ float sigm_(float x) { return 1.f / (1.f + __expf(-x)); }
__device__ __forceinline__ float tanh_(float x) { return 1.f - 2.f / (__expf(2.f * x) + 1.f); }

template <typename T>
__device__ __forceinline__ void st_agent(T* p, T v) {
  __hip_atomic_store(p, v, __ATOMIC_RELAXED, __HIP_MEMORY_SCOPE_AGENT);
}
template <typename T>
__device__ __forceinline__ T ld_agent(const T* p) {
  return __hip_atomic_load(p, __ATOMIC_RELAXED, __HIP_MEMORY_SCOPE_AGENT);
}
__device__ __forceinline__ u64 pack2f(float a, float b) {
  return (u64)__float_as_uint(a) | ((u64)__float_as_uint(b) << 32);
}
__device__ __forceinline__ u64 pack4bf(f32x4 v) {
  return (u64)f2bf(v[0]) | ((u64)f2bf(v[1]) << 16) |
         ((u64)f2bf(v[2]) << 32) | ((u64)f2bf(v[3]) << 48);
}

// ---------- prologue kernels ----------
__global__ void fc_kernel(const float* __restrict__ x, const float* __restrict__ w,
                          const float* __restrict__ bias, float* __restrict__ z) {
  int idx = blockIdx.x * 256 + threadIdx.x;    // 131072 = 128*1024
  int b = idx >> 10, i = idx & 1023;
  const float* xr = x + b * 256;
  const float* wr = w + i * 256;
  float acc = bias[i];
  #pragma unroll 4
  for (int o = 0; o < 256; ++o) acc += xr[o] * wr[o];
  z[idx] = acc;
}

__global__ void gx0_kernel(const float* __restrict__ z, const float* __restrict__ Wih0,
                           const float* __restrict__ bih, const float* __restrict__ bhh,
                           float* __restrict__ gx0) {
  int idx = blockIdx.x * 256 + threadIdx.x;    // 524288 = 128*4096
  int b = idx >> 12, j = idx & 4095;
  const float* zr = z + b * 1024;
  const float* wr = Wih0 + (size_t)j * 1024;
  float acc = bih[j] + bhh[j];
  #pragma unroll 4
  for (int k = 0; k < 1024; ++k) acc += zr[k] * wr[k];
  gx0[idx] = acc;
}

// ---------- persistent fused 2-layer LSTM, dataflow-synchronized ----------
// 192 blocks x 512 threads, 1 block/CU (LDS-limited: 118 KiB). Roles:
//   role0: layer0 recurrence (h0(t-1) -> h0(t))
//   role1: layer1 input-side (h0(t) -> pa(t), point-to-point to role2 partner)
//   role2: layer1 recurrence + pointwise + out (pa(t), h1(t-1) -> h1(t))
// RESUBMIT of R3 (container failed twice = infra flake; protocol identical
// to R2 which passed; barriers convergent; attribute satisfiable).
// vs R2 (spill fix ONLY — structure unchanged):
// 1. amdgpu_waves_per_eu(2,2): R2's __launch_bounds__(512,2) let the
//    compiler's occupancy heuristic target 4 waves/EU (128 VGPRs), spilling
//    the 128-VGPR breg tile to scratch (VGPR_Count=128, 2x regression).
//    LDS already caps the CU at 2 waves/SIMD, so the spill bought nothing.
//    min=max=2 waves/EU => 256-reg budget, heuristic pinned.
// 2. pa64 live-range trim: loads moved from before the reduction to just
//    before the pointwise loop (latency hides under 32 iterations of
//    exp-heavy VALU; frees 32 regs on the max-liveness path).
__global__ __launch_bounds__(512) __attribute__((amdgpu_waves_per_eu(2, 2)))
void lstm_persist(const float* __restrict__ Whh0, const float* __restrict__ Wih1,
                  const float* __restrict__ Whh1, const float* __restrict__ gx0,
                  const float* __restrict__ bih1, const float* __restrict__ bhh1,
                  u16* __restrict__ h0ring, u16* __restrict__ h1ring,
                  float* __restrict__ pabuf, float* __restrict__ out,
                  int* __restrict__ h0flag, int* __restrict__ paflag,
                  int* __restrict__ h1flag) {
  __shared__ __align__(16) u16 wlds2[2][2048][8];      // 64 KiB (gates 2,3)
  __shared__ __align__(16) float red[4][64][44];       // 44 KiB (acc0+acc1 merged)
  __shared__ __align__(16) float stage[128][20];       // 10 KiB (h staging)

  const int bid = blockIdx.x;
  const int role = bid >> 6;
  const int cslice = bid & 63;
  const int cb = cslice * 16;        // h-col base
  const int tid = threadIdx.x;
  const int w = tid >> 6;            // wave 0..7
  const int lane = tid & 63;
  const int l15 = lane & 15;
  const int q = lane >> 4;
  const int Mg = w & 3;              // M-group: batches Mg*32..+32
  const int kh = w >> 2;             // K-half

  const float* Wsrc = (role == 0) ? Whh0 : (role == 1) ? Wih1 : Whh1;

  // ---- stage W gates 2,3 fp32 -> bf16 -> LDS (once) ----
  {
    const int r = tid >> 4;          // 0..31
    const int g2 = r >> 4, n = r & 15;
    const int k0 = (tid & 15) * 64;
    const float* src = Wsrc + (((size_t)((2 + g2) * 1024 + cb + n)) << 10) + k0;
    for (int k = 0; k < 64; k += 4) {
      float4 v = *(const float4*)(src + k);
      ushort4 o;
      o.x = f2bf(v.x); o.y = f2bf(v.y); o.z = f2bf(v.z); o.w = f2bf(v.w);
      const int kk = k0 + k;
      *(ushort4*)&wlds2[g2][((kk >> 3) << 4) + n][kk & 7] = o;
    }
  }

  // ---- preload W gates 0,1 fragments into registers (once) ----
  bf16x8 breg[2][16];
  {
    #pragma unroll
    for (int g = 0; g < 2; ++g) {
      const float* wrow = Wsrc + (((size_t)(g * 1024 + cb + l15)) << 10) + kh * 512 + q * 8;
      #pragma unroll
      for (int kk = 0; kk < 16; ++kk) {
        float4 v0 = *(const float4*)(wrow + kk * 32);
        float4 v1 = *(const float4*)(wrow + kk * 32 + 4);
        union { bf16x8 v; u16 u[8]; } tmp;
        tmp.u[0] = f2bf(v0.x); tmp.u[1] = f2bf(v0.y);
        tmp.u[2] = f2bf(v0.z); tmp.u[3] = f2bf(v0.w);
        tmp.u[4] = f2bf(v1.x); tmp.u[5] = f2bf(v1.y);
        tmp.u[6] = f2bf(v1.z); tmp.u[7] = f2bf(v1.w);
        breg[g][kk] = tmp.v;
      }
    }
  }

  // ---- per-thread persistent state ----
  float c_st[2][4];
  #pragma unroll
  for (int mt = 0; mt < 2; ++mt)
    #pragma unroll
    for (int r = 0; r < 4; ++r) c_st[mt][r] = 0.f;

  float gx[2][4][4];                 // role0: gx0 base slice
  float b1[4];                       // role2: bias
  if (role == 0 && w < 4) {
    #pragma unroll
    for (int mt = 0; mt < 2; ++mt)
      #pragma unroll
      for (int g = 0; g < 4; ++g)
        #pragma unroll
        for (int r = 0; r < 4; ++r)
          gx[mt][g][r] = gx0[(size_t)(w * 32 + mt * 16 + q * 4 + r) * 4096 + g * 1024 + cb + l15];
  }
  if (role == 2 && w < 4) {
    #pragma unroll
    for (int g = 0; g < 4; ++g)
      b1[g] = bih1[g * 1024 + cb + l15] + bhh1[g * 1024 + cb + l15];
  }
  __syncthreads();                   // wlds2 ready

  const size_t HSLOT = (size_t)128 * 1024;   // elems per h ring slot

  for (int t = 0; t < T_SEQ; ++t) {
    const int sA = (t + 3) & 3;      // slot holding h(t-1)
    const int sW = t & 3;            // slot this step writes

    // ---- per-wave dataflow wait: only THIS wave's 32 K-producers ----
    // role0: h0(t-1) (flag>=t). role1: h0(t) (flag>=t+1). role2: h1(t-1).
    // (role2's h1 slot-overwrite safety is subsumed: peers' flag>=t >= t-3.)
    {
      const int pl = kh * 32 + (lane & 31);
      const int* fl = (role == 2) ? h1flag : h0flag;
      const int thr = (role == 1) ? t + 1 : t;
      bool ok;
      do {
        int f = ld_agent(fl + pl * FPAD);
        ok = __all(f >= thr);
        if (!ok) __builtin_amdgcn_s_sleep(1);
      } while (!ok);
      __builtin_amdgcn_fence(__ATOMIC_ACQUIRE, "agent");   // per-wave L1 inv
    }

    const u16* A = (role == 0) ? h0ring + (size_t)sA * HSLOT
                 : (role == 1) ? h0ring + (size_t)sW * HSLOT
                               : h1ring + (size_t)sA * HSLOT;

    const int kbase = kh * 512;
    const u16* Ap = A + (((size_t)(Mg * 32 + l15)) << 10) + kbase + q * 8;
    const int cellbase = ((kbase >> 3) + q) * 16 + l15;   // + kk*64

    f32x4 acc0[4] = {{0.f,0.f,0.f,0.f},{0.f,0.f,0.f,0.f},{0.f,0.f,0.f,0.f},{0.f,0.f,0.f,0.f}};
    f32x4 acc1[4] = {{0.f,0.f,0.f,0.f},{0.f,0.f,0.f,0.f},{0.f,0.f,0.f,0.f},{0.f,0.f,0.f,0.f}};

    #pragma unroll
    for (int kk = 0; kk < 16; ++kk) {
      bf16x8 a0 = *(const bf16x8*)(Ap + kk * 32);
      bf16x8 a1 = *(const bf16x8*)(Ap + (16 << 10) + kk * 32);
      acc0[0] = __builtin_amdgcn_mfma_f32_16x16x32_bf16(a0, breg[0][kk], acc0[0], 0, 0, 0);
      acc1[0] = __builtin_amdgcn_mfma_f32_16x16x32_bf16(a1, breg[0][kk], acc1[0], 0, 0, 0);
      acc0[1] = __builtin_amdgcn_mfma_f32_16x16x32_bf16(a0, breg[1][kk], acc0[1], 0, 0, 0);
      acc1[1] = __builtin_amdgcn_mfma_f32_16x16x32_bf16(a1, breg[1][kk], acc1[1], 0, 0, 0);
      bf16x8 b2 = *(const bf16x8*)&wlds2[0][cellbase + kk * 64][0];
      acc0[2] = __builtin_amdgcn_mfma_f32_16x16x32_bf16(a0, b2, acc0[2], 0, 0, 0);
      acc1[2] = __builtin_amdgcn_mfma_f32_16x16x32_bf16(a1, b2, acc1[2], 0, 0, 0);
      bf16x8 b3 = *(const bf16x8*)&wlds2[1][cellbase + kk * 64][0];
      acc0[3] = __builtin_amdgcn_mfma_f32_16x16x32_bf16(a0, b3, acc0[3], 0, 0, 0);
      acc1[3] = __builtin_amdgcn_mfma_f32_16x16x32_bf16(a1, b3, acc1[3], 0, 0, 0);
    }

    // ---- K-half reduction via LDS (single merged round) ----
    if (w >= 4) {
      #pragma unroll
      for (int g = 0; g < 4; ++g) {
        *(f32x4*)&red[w - 4][lane][g * 4]      = acc0[g];
        *(f32x4*)&red[w - 4][lane][16 + g * 4] = acc1[g];
      }
    }
    __syncthreads();                 // sync#1: red ready
    if (w < 4) {
      #pragma unroll
      for (int g = 0; g < 4; ++g) {
        acc0[g] += *(const f32x4*)&red[w][lane][g * 4];
        acc1[g] += *(const f32x4*)&red[w][lane][16 + g * 4];
      }

      if (role == 1) {
        // backpressure: partner role2 published h1(t-4) => pabuf slot sW free
        while (ld_agent(h1flag + cslice * FPAD) < t - 3) __builtin_amdgcn_s_sleep(1);
        float* pw = pabuf + (size_t)sW * 524288 + (size_t)(cslice * 4 + w) * 2048;
        #pragma unroll
        for (int g = 0; g < 4; ++g) {
          st_agent((u64*)pw + g * 128 + lane * 2,           pack2f(acc0[g][0], acc0[g][1]));
          st_agent((u64*)pw + g * 128 + lane * 2 + 1,       pack2f(acc0[g][2], acc0[g][3]));
          st_agent((u64*)pw + (4 + g) * 128 + lane * 2,     pack2f(acc1[g][0], acc1[g][1]));
          st_agent((u64*)pw + (4 + g) * 128 + lane * 2 + 1, pack2f(acc1[g][2], acc1[g][3]));
        }
      } else {
        // role2: pa(t) wait + loads HERE (short live range; latency hides
        // under the 32-iteration exp-heavy pointwise loop below)
        u64 pa64[16];
        if (role == 2) {
          const float* pr = pabuf + (size_t)sW * 524288 + (size_t)(cslice * 4 + w) * 2048;
          while (ld_agent(paflag + cslice * FPAD) < t + 1) __builtin_amdgcn_s_sleep(1);
          #pragma unroll
          for (int j = 0; j < 8; ++j) {
            pa64[j * 2]     = ld_agent((const u64*)pr + j * 128 + lane * 2);
            pa64[j * 2 + 1] = ld_agent((const u64*)pr + j * 128 + lane * 2 + 1);
          }
        }
        #pragma unroll
        for (int mt = 0; mt < 2; ++mt) {
          #pragma unroll
          for (int r = 0; r < 4; ++r) {
            float xi, xf, xg, xo;
            f32x4* a = mt ? acc1 : acc0;
            if (role == 0) {
              xi = a[0][r] + gx[mt][0][r];
              xf = a[1][r] + gx[mt][1][r];
              xg = a[2][r] + gx[mt][2][r];
              xo = a[3][r] + gx[mt][3][r];
            } else {
              const int h2 = r >> 1, lo = r & 1;
              auto up = [&](int j) {
                u64 v = pa64[j * 2 + h2];
                return __uint_as_float(lo ? (unsigned)(v >> 32) : (unsigned)v);
              };
              xi = a[0][r] + up(mt * 4 + 0) + b1[0];
              xf = a[1][r] + up(mt * 4 + 1) + b1[1];
              xg = a[2][r] + up(mt * 4 + 2) + b1[2];
              xo = a[3][r] + up(mt * 4 + 3) + b1[3];
            }
            float i_ = sigm_(xi), f_ = sigm_(xf), g_ = tanh_(xg), o_ = sigm_(xo);
            float cn = f_ * c_st[mt][r] + i_ * g_;
            c_st[mt][r] = cn;
            float h = o_ * tanh_(cn);
            stage[w * 32 + mt * 16 + q * 4 + r][l15] = h;   // f32 h to LDS stage
          }
        }
      }
    }

    if (role != 1) {
      __syncthreads();                       // sync#2: stage[] ready
      if (role == 0) {
        // backpressure: all 64 role1 blocks read h0(t-4) => slot sW free
        bool ok;
        do {
          int f = ld_agent(paflag + lane * FPAD);
          ok = __all(f >= t - 3);
          if (!ok) __builtin_amdgcn_s_sleep(1);
        } while (!ok);
      }
      const int row = tid >> 2, qt = tid & 3;
      f32x4 v = *(const f32x4*)&stage[row][qt * 4];
      u64 pk = pack4bf(v);
      if (role == 0) {
        st_agent((u64*)(h0ring + (size_t)sW * HSLOT + ((size_t)row << 10) + cb) + qt, pk);
      } else {
        st_agent((u64*)(h1ring + (size_t)sW * HSLOT + ((size_t)row << 10) + cb) + qt, pk);
      }
      __syncthreads();                       // sync#3: per-wave vmcnt drain
      if (tid == 0) {
        if (role == 0) st_agent(h0flag + cslice * FPAD, t + 1);
        else           st_agent(h1flag + cslice * FPAD, t + 1);
      }
      if (role == 2) {
        // out has NO cross-block reader: plain cached store, after flag
        *(f32x4*)(out + (size_t)row * ((size_t)T_SEQ * 1024) + (size_t)t * 1024 + cb + qt * 4) = v;
      }
    } else {
      __syncthreads();                       // sync#2: pa store drain
      if (tid == 0) st_agent(paflag + cslice * FPAD, t + 1);
    }
  }
}

// ---------- launch ----------
extern "C" void kernel_launch(void* const* d_in, const int* in_sizes, int n_in,
                              void* d_out, int out_size, void* d_ws, size_t ws_size,
                              hipStream_t stream) {
  (void)in_sizes; (void)n_in; (void)out_size; (void)ws_size;
  const float* x    = (const float*)d_in[0];
  const float* fc_w = (const float*)d_in[1];
  const float* fc_b = (const float*)d_in[2];
  const float* Wih0 = (const float*)d_in[3];
  const float* Whh0 = (const float*)d_in[4];
  const float* bih0 = (const float*)d_in[5];
  const float* bhh0 = (const float*)d_in[6];
  const float* Wih1 = (const float*)d_in[7];
  const float* Whh1 = (const float*)d_in[8];
  const float* bih1 = (const float*)d_in[9];
  const float* bhh1 = (const float*)d_in[10];
  float* out = (float*)d_out;

  char* ws = (char*)d_ws;
  size_t off = 0;
  auto alloc = [&](size_t bytes) -> void* {
    void* p = ws + off;
    off += (bytes + 255) & ~(size_t)255;
    return p;
  };
  float* z      = (float*)alloc((size_t)128 * 1024 * 4);
  float* gx0    = (float*)alloc((size_t)128 * 4096 * 4);
  u16*   h0ring = (u16*)alloc((size_t)RSLOT * 128 * 1024 * 2);
  u16*   h1ring = (u16*)alloc((size_t)RSLOT * 128 * 1024 * 2);
  float* pabuf  = (float*)alloc((size_t)RSLOT * 524288 * 4);
  int*   h0flag = (int*)alloc((size_t)64 * FPAD * 4);
  int*   paflag = (int*)alloc((size_t)64 * FPAD * 4);
  int*   h1flag = (int*)alloc((size_t)64 * FPAD * 4);

  hipMemsetAsync(h0ring, 0, (size_t)RSLOT * 128 * 1024 * 2, stream);
  hipMemsetAsync(h1ring, 0, (size_t)RSLOT * 128 * 1024 * 2, stream);
  hipMemsetAsync(h0flag, 0, (size_t)64 * FPAD * 4, stream);
  hipMemsetAsync(paflag, 0, (size_t)64 * FPAD * 4, stream);
  hipMemsetAsync(h1flag, 0, (size_t)64 * FPAD * 4, stream);

  fc_kernel<<<512, 256, 0, stream>>>(x, fc_w, fc_b, z);
  gx0_kernel<<<2048, 256, 0, stream>>>(z, Wih0, bih0, bhh0, gx0);

  lstm_persist<<<NBLK, 512, 0, stream>>>(Whh0, Wih1, Whh1, gx0, bih1, bhh1,
                                         h0ring, h1ring, pabuf, out,
                                         h0flag, paflag, h1flag);
}

// Round 5
// 11129.617 us; speedup vs baseline: 1.1992x; 1.1992x over previous
//
#include <hip/hip_runtime.h>

typedef __attribute__((ext_vector_type(8))) short bf16x8;   // 8 bf16 (4 VGPRs)
typedef __attribute__((ext_vector_type(4))) float f32x4;
typedef unsigned short u16;
typedef unsigned long long u64;

#define T_SEQ 512
#define NBLK  192
#define FPAD  16        // ints per flag slot = one 64B line
#define RSLOT 4         // ring depth for h0ring / h1ring / pabuf

__device__ __forceinline__ u16 f2bf(float f) {
  unsigned int u = __float_as_uint(f);
  u += 0x7fffu + ((u >> 16) & 1u);           // RNE
  return (u16)(u >> 16);
}
__device__ __forceinline__ float sigm_(float x) { return 1.f / (1.f + __expf(-x)); }
__device__ __forceinline__ float tanh_(float x) { return 1.f - 2.f / (__expf(2.f * x) + 1.f); }

template <typename T>
__device__ __forceinline__ void st_agent(T* p, T v) {
  __hip_atomic_store(p, v, __ATOMIC_RELAXED, __HIP_MEMORY_SCOPE_AGENT);
}
template <typename T>
__device__ __forceinline__ T ld_agent(const T* p) {
  return __hip_atomic_load(p, __ATOMIC_RELAXED, __HIP_MEMORY_SCOPE_AGENT);
}
__device__ __forceinline__ u64 pack2f(float a, float b) {
  return (u64)__float_as_uint(a) | ((u64)__float_as_uint(b) << 32);
}
__device__ __forceinline__ u64 pack4bf(f32x4 v) {
  return (u64)f2bf(v[0]) | ((u64)f2bf(v[1]) << 16) |
         ((u64)f2bf(v[2]) << 32) | ((u64)f2bf(v[3]) << 48);
}

// ---------- prologue kernels ----------
__global__ void fc_kernel(const float* __restrict__ x, const float* __restrict__ w,
                          const float* __restrict__ bias, float* __restrict__ z) {
  int idx = blockIdx.x * 256 + threadIdx.x;    // 131072 = 128*1024
  int b = idx >> 10, i = idx & 1023;
  const float* xr = x + b * 256;
  const float* wr = w + i * 256;
  float acc = bias[i];
  #pragma unroll 4
  for (int o = 0; o < 256; ++o) acc += xr[o] * wr[o];
  z[idx] = acc;
}

__global__ void gx0_kernel(const float* __restrict__ z, const float* __restrict__ Wih0,
                           const float* __restrict__ bih, const float* __restrict__ bhh,
                           float* __restrict__ gx0) {
  int idx = blockIdx.x * 256 + threadIdx.x;    // 524288 = 128*4096
  int b = idx >> 12, j = idx & 4095;
  const float* zr = z + b * 1024;
  const float* wr = Wih0 + (size_t)j * 1024;
  float acc = bih[j] + bhh[j];
  #pragma unroll 4
  for (int k = 0; k < 1024; ++k) acc += zr[k] * wr[k];
  gx0[idx] = acc;
}

// ---------- persistent fused 2-layer LSTM, dataflow-synchronized ----------
// 192 blocks x 512 threads, 1 block/CU (LDS-limited: 158 KiB). Roles:
//   role0: layer0 recurrence (h0(t-1) -> h0(t))
//   role1: layer1 input-side (h0(t) -> pa(t), point-to-point to role2 partner)
//   role2: layer1 recurrence + pointwise + out (pa(t), h1(t-1) -> h1(t))
// BASE: the R1 kernel (best verified: 6.37ms, VGPR=108, no spill). The
// breg-in-registers experiments (R2-R4) hit a hard 128-VGPR allocation and
// spilled to scratch (WRITE_SIZE +1.1GB) — reverted entirely.
// vs R1, exactly three register-neutral sync edits:
// 1. PER-WAVE FRONT POLL, no front barrier: each wave polls only its own
//    K-half's 32 producer flag lines, acquire-fences, and starts its
//    A-loads. (R1: wave0 polled 64-128 lines, then a block-wide barrier
//    coupled all waves to the slowest poll.) Cross-step LDS hazards (red,
//    stage) stay protected by step t-1's stage/drain barriers: every red/
//    stage WRITE at t is behind a block-wide barrier that follows the last
//    t-1 READ of that buffer.
// 2. BACKPRESSURE OFF THE POLL: role0's paflag>=t-3 check (h0 slot reuse)
//    moves to just before the h-store; role1's partner h1flag>=t-3 check
//    stays at its pa-store. Both reference 4-step-old flags (~always
//    satisfied, off the critical path).
//    Slot-safety audit (slot-less monotone flags, value = t+1):
//      h0 slot sW readers: role0 peers at step t-3 (done: front wait saw
//      flag>=t > t-3 block-wide before store-phase) and role1 at t-4
//      (done: paflag>=t-3) and role1 at t (waits h0flag>=t+1, published
//      after the store). h1 analogous. pa slot sW reader: partner role2 at
//      t-4 (done: h1flag>=t-3) and t (waits paflag>=t+1).
// 3. role2's out store moved after the flag publish (no cross-block
//    reader; overlaps next step's poll).
__global__ __launch_bounds__(512, 2)
void lstm_persist(const float* __restrict__ Whh0, const float* __restrict__ Wih1,
                  const float* __restrict__ Whh1, const float* __restrict__ gx0,
                  const float* __restrict__ bih1, const float* __restrict__ bhh1,
                  u16* __restrict__ h0ring, u16* __restrict__ h1ring,
                  float* __restrict__ pabuf, float* __restrict__ out,
                  int* __restrict__ h0flag, int* __restrict__ paflag,
                  int* __restrict__ h1flag) {
  __shared__ __align__(16) u16 wlds[4][2048][8];       // 128 KiB (frag-major W)
  __shared__ __align__(16) float red[4][64][20];       // 20 KiB (padded rows)
  __shared__ __align__(16) float stage[128][20];       // 10 KiB (h staging)

  const int bid = blockIdx.x;
  const int role = bid >> 6;
  const int cslice = bid & 63;
  const int cb = cslice * 16;        // h-col base
  const int tid = threadIdx.x;
  const int w = tid >> 6;            // wave 0..7
  const int lane = tid & 63;
  const int l15 = lane & 15;
  const int q = lane >> 4;
  const int Mg = w & 3;              // M-group: batches Mg*32..+32
  const int kh = w >> 2;             // K-half

  // ---- stage W slice fp32 -> bf16 -> LDS (once) ----
  {
    const float* Wsrc = (role == 0) ? Whh0 : (role == 1) ? Wih1 : Whh1;
    const int r = tid >> 3;          // 0..63: row within slice
    const int g = r >> 4, n = r & 15;
    const int k0 = (tid & 7) * 128;
    const float* src = Wsrc + (((size_t)(g * 1024 + cb + n)) << 10) + k0;
    for (int k = 0; k < 128; k += 4) {
      float4 v = *(const float4*)(src + k);
      ushort4 o;
      o.x = f2bf(v.x); o.y = f2bf(v.y); o.z = f2bf(v.z); o.w = f2bf(v.w);
      const int kk = k0 + k;
      *(ushort4*)&wlds[g][((kk >> 3) << 4) + n][kk & 7] = o;
    }
  }

  // ---- per-thread persistent state ----
  float c_st[2][4];
  #pragma unroll
  for (int mt = 0; mt < 2; ++mt)
    #pragma unroll
    for (int r = 0; r < 4; ++r) c_st[mt][r] = 0.f;

  float gx[2][4][4];                 // role0: gx0 base slice
  float b1[4];                       // role2: bias
  if (role == 0 && w < 4) {
    #pragma unroll
    for (int mt = 0; mt < 2; ++mt)
      #pragma unroll
      for (int g = 0; g < 4; ++g)
        #pragma unroll
        for (int r = 0; r < 4; ++r)
          gx[mt][g][r] = gx0[(size_t)(w * 32 + mt * 16 + q * 4 + r) * 4096 + g * 1024 + cb + l15];
  }
  if (role == 2 && w < 4) {
    #pragma unroll
    for (int g = 0; g < 4; ++g)
      b1[g] = bih1[g * 1024 + cb + l15] + bhh1[g * 1024 + cb + l15];
  }
  __syncthreads();                   // wlds ready

  const size_t HSLOT = (size_t)128 * 1024;   // elems per h ring slot

  for (int t = 0; t < T_SEQ; ++t) {
    const int sA = (t + 3) & 3;      // slot holding h(t-1)
    const int sW = t & 3;            // slot this step writes

    // ---- per-wave dataflow wait: only THIS wave's 32 K-producers ----
    // role0: h0(t-1) (flag>=t). role1: h0(t) (flag>=t+1). role2: h1(t-1).
    {
      const int pl = kh * 32 + (lane & 31);
      const int* fl = (role == 2) ? h1flag : h0flag;
      const int thr = (role == 1) ? t + 1 : t;
      bool ok;
      do {
        int f = ld_agent(fl + pl * FPAD);
        ok = __all(f >= thr);
        if (!ok) __builtin_amdgcn_s_sleep(1);
      } while (!ok);
      __builtin_amdgcn_fence(__ATOMIC_ACQUIRE, "agent");   // per-wave L1 inv
    }

    const u16* A = (role == 0) ? h0ring + (size_t)sA * HSLOT
                 : (role == 1) ? h0ring + (size_t)sW * HSLOT
                               : h1ring + (size_t)sA * HSLOT;

    const int kbase = kh * 512;
    const u16* Ap = A + (((size_t)(Mg * 32 + l15)) << 10) + kbase + q * 8;
    const int cellbase = ((kbase >> 3) + q) * 16 + l15;   // + kk*64

    f32x4 acc0[4] = {{0.f,0.f,0.f,0.f},{0.f,0.f,0.f,0.f},{0.f,0.f,0.f,0.f},{0.f,0.f,0.f,0.f}};
    f32x4 acc1[4] = {{0.f,0.f,0.f,0.f},{0.f,0.f,0.f,0.f},{0.f,0.f,0.f,0.f},{0.f,0.f,0.f,0.f}};

    #pragma unroll
    for (int kk = 0; kk < 16; ++kk) {
      bf16x8 a0 = *(const bf16x8*)(Ap + kk * 32);
      bf16x8 a1 = *(const bf16x8*)(Ap + (16 << 10) + kk * 32);
      #pragma unroll
      for (int g = 0; g < 4; ++g) {
        bf16x8 b = *(const bf16x8*)&wlds[g][cellbase + kk * 64][0];
        acc0[g] = __builtin_amdgcn_mfma_f32_16x16x32_bf16(a0, b, acc0[g], 0, 0, 0);
        acc1[g] = __builtin_amdgcn_mfma_f32_16x16x32_bf16(a1, b, acc1[g], 0, 0, 0);
      }
    }

    // role2: pa(t) wait + issue loads early (u64 atomics; compiler inserts
    // the wait before first use, the LDS reduction hides the latency)
    u64 pa64[16];
    const float* pr = pabuf + (size_t)sW * 524288 + (size_t)(cslice * 4 + w) * 2048;
    if (role == 2 && w < 4) {
      while (ld_agent(paflag + cslice * FPAD) < t + 1) __builtin_amdgcn_s_sleep(1);
      #pragma unroll
      for (int j = 0; j < 8; ++j) {
        pa64[j * 2]     = ld_agent((const u64*)pr + j * 128 + lane * 2);
        pa64[j * 2 + 1] = ld_agent((const u64*)pr + j * 128 + lane * 2 + 1);
      }
    }

    // ---- K-half reduction via LDS (two rounds, 20-word padded rows) ----
    if (w >= 4) {
      #pragma unroll
      for (int g = 0; g < 4; ++g) *(f32x4*)&red[w - 4][lane][g * 4] = acc0[g];
    }
    __syncthreads();
    if (w < 4) {
      #pragma unroll
      for (int g = 0; g < 4; ++g) acc0[g] += *(const f32x4*)&red[w][lane][g * 4];
    }
    __syncthreads();
    if (w >= 4) {
      #pragma unroll
      for (int g = 0; g < 4; ++g) *(f32x4*)&red[w - 4][lane][g * 4] = acc1[g];
    }
    __syncthreads();
    if (w < 4) {
      #pragma unroll
      for (int g = 0; g < 4; ++g) acc1[g] += *(const f32x4*)&red[w][lane][g * 4];

      if (role == 1) {
        // backpressure: partner role2 published h1(t-4) => pabuf slot sW free
        while (ld_agent(h1flag + cslice * FPAD) < t - 3) __builtin_amdgcn_s_sleep(1);
        float* pw = pabuf + (size_t)sW * 524288 + (size_t)(cslice * 4 + w) * 2048;
        #pragma unroll
        for (int g = 0; g < 4; ++g) {
          st_agent((u64*)pw + g * 128 + lane * 2,           pack2f(acc0[g][0], acc0[g][1]));
          st_agent((u64*)pw + g * 128 + lane * 2 + 1,       pack2f(acc0[g][2], acc0[g][3]));
          st_agent((u64*)pw + (4 + g) * 128 + lane * 2,     pack2f(acc1[g][0], acc1[g][1]));
          st_agent((u64*)pw + (4 + g) * 128 + lane * 2 + 1, pack2f(acc1[g][2], acc1[g][3]));
        }
      } else {
        #pragma unroll
        for (int mt = 0; mt < 2; ++mt) {
          #pragma unroll
          for (int r = 0; r < 4; ++r) {
            float xi, xf, xg, xo;
            f32x4* a = mt ? acc1 : acc0;
            if (role == 0) {
              xi = a[0][r] + gx[mt][0][r];
              xf = a[1][r] + gx[mt][1][r];
              xg = a[2][r] + gx[mt][2][r];
              xo = a[3][r] + gx[mt][3][r];
            } else {
              const int h2 = r >> 1, lo = r & 1;
              auto up = [&](int j) {
                u64 v = pa64[j * 2 + h2];
                return __uint_as_float(lo ? (unsigned)(v >> 32) : (unsigned)v);
              };
              xi = a[0][r] + up(mt * 4 + 0) + b1[0];
              xf = a[1][r] + up(mt * 4 + 1) + b1[1];
              xg = a[2][r] + up(mt * 4 + 2) + b1[2];
              xo = a[3][r] + up(mt * 4 + 3) + b1[3];
            }
            float i_ = sigm_(xi), f_ = sigm_(xf), g_ = tanh_(xg), o_ = sigm_(xo);
            float cn = f_ * c_st[mt][r] + i_ * g_;
            c_st[mt][r] = cn;
            float h = o_ * tanh_(cn);
            stage[w * 32 + mt * 16 + q * 4 + r][l15] = h;   // f32 h to LDS stage
          }
        }
      }
    }

    if (role != 1) {
      __syncthreads();                       // stage[] ready
      if (role == 0) {
        // backpressure: all 64 role1 blocks read h0(t-4) => slot sW free
        // (wave-parallel, 4-step-old flags — ~always one iteration)
        bool ok;
        do {
          int f = ld_agent(paflag + lane * FPAD);
          ok = __all(f >= t - 3);
          if (!ok) __builtin_amdgcn_s_sleep(1);
        } while (!ok);
      }
      const int row = tid >> 2, qt = tid & 3;
      f32x4 v = *(const f32x4*)&stage[row][qt * 4];
      u64 pk = pack4bf(v);
      if (role == 0) {
        st_agent((u64*)(h0ring + (size_t)sW * HSLOT + ((size_t)row << 10) + cb) + qt, pk);
      } else {
        st_agent((u64*)(h1ring + (size_t)sW * HSLOT + ((size_t)row << 10) + cb) + qt, pk);
      }
      __syncthreads();                       // per-wave vmcnt drain
      if (tid == 0) {
        if (role == 0) st_agent(h0flag + cslice * FPAD, t + 1);
        else           st_agent(h1flag + cslice * FPAD, t + 1);
      }
      if (role == 2) {
        // out has NO cross-block reader: plain cached store, after flag
        *(f32x4*)(out + (size_t)row * ((size_t)T_SEQ * 1024) + (size_t)t * 1024 + cb + qt * 4) = v;
      }
    } else {
      __syncthreads();                       // pa store drain
      if (tid == 0) st_agent(paflag + cslice * FPAD, t + 1);
    }
  }
}

// ---------- launch ----------
extern "C" void kernel_launch(void* const* d_in, const int* in_sizes, int n_in,
                              void* d_out, int out_size, void* d_ws, size_t ws_size,
                              hipStream_t stream) {
  (void)in_sizes; (void)n_in; (void)out_size; (void)ws_size;
  const float* x    = (const float*)d_in[0];
  const float* fc_w = (const float*)d_in[1];
  const float* fc_b = (const float*)d_in[2];
  const float* Wih0 = (const float*)d_in[3];
  const float* Whh0 = (const float*)d_in[4];
  const float* bih0 = (const float*)d_in[5];
  const float* bhh0 = (const float*)d_in[6];
  const float* Wih1 = (const float*)d_in[7];
  const float* Whh1 = (const float*)d_in[8];
  const float* bih1 = (const float*)d_in[9];
  const float* bhh1 = (const float*)d_in[10];
  float* out = (float*)d_out;

  char* ws = (char*)d_ws;
  size_t off = 0;
  auto alloc = [&](size_t bytes) -> void* {
    void* p = ws + off;
    off += (bytes + 255) & ~(size_t)255;
    return p;
  };
  float* z      = (float*)alloc((size_t)128 * 1024 * 4);
  float* gx0    = (float*)alloc((size_t)128 * 4096 * 4);
  u16*   h0ring = (u16*)alloc((size_t)RSLOT * 128 * 1024 * 2);
  u16*   h1ring = (u16*)alloc((size_t)RSLOT * 128 * 1024 * 2);
  float* pabuf  = (float*)alloc((size_t)RSLOT * 524288 * 4);
  int*   h0flag = (int*)alloc((size_t)64 * FPAD * 4);
  int*   paflag = (int*)alloc((size_t)64 * FPAD * 4);
  int*   h1flag = (int*)alloc((size_t)64 * FPAD * 4);

  hipMemsetAsync(h0ring, 0, (size_t)RSLOT * 128 * 1024 * 2, stream);
  hipMemsetAsync(h1ring, 0, (size_t)RSLOT * 128 * 1024 * 2, stream);
  hipMemsetAsync(h0flag, 0, (size_t)64 * FPAD * 4, stream);
  hipMemsetAsync(paflag, 0, (size_t)64 * FPAD * 4, stream);
  hipMemsetAsync(h1flag, 0, (size_t)64 * FPAD * 4, stream);

  fc_kernel<<<512, 256, 0, stream>>>(x, fc_w, fc_b, z);
  gx0_kernel<<<2048, 256, 0, stream>>>(z, Wih0, bih0, bhh0, gx0);

  lstm_persist<<<NBLK, 512, 0, stream>>>(Whh0, Wih1, Whh1, gx0, bih1, bhh1,
                                         h0ring, h1ring, pabuf, out,
                                         h0flag, paflag, h1flag);
}

// Round 7
// 8391.761 us; speedup vs baseline: 1.5904x; 1.3263x over previous
//
#include <hip/hip_runtime.h>

typedef __attribute__((ext_vector_type(8))) short bf16x8;   // 8 bf16 (4 VGPRs)
typedef __attribute__((ext_vector_type(4))) float f32x4;
typedef unsigned short u16;
typedef unsigned long long u64;

#define T_SEQ 512
#define NBLK  192
#define RSLOT 4         // ring depth for h0ring / h1ring / pabuf

__device__ __forceinline__ u16 f2bf(float f) {
  unsigned int u = __float_as_uint(f);
  u += 0x7fffu + ((u >> 16) & 1u);           // RNE
  return (u16)(u >> 16);
}
__device__ __forceinline__ float sigm_(float x) { return 1.f / (1.f + __expf(-x)); }
__device__ __forceinline__ float tanh_(float x) { return 1.f - 2.f / (__expf(2.f * x) + 1.f); }

template <typename T>
__device__ __forceinline__ void st_agent(T* p, T v) {
  __hip_atomic_store(p, v, __ATOMIC_RELAXED, __HIP_MEMORY_SCOPE_AGENT);
}
template <typename T>
__device__ __forceinline__ T ld_agent(const T* p) {
  return __hip_atomic_load(p, __ATOMIC_RELAXED, __HIP_MEMORY_SCOPE_AGENT);
}
__device__ __forceinline__ u64 pack2f(float a, float b) {
  return (u64)__float_as_uint(a) | ((u64)__float_as_uint(b) << 32);
}
__device__ __forceinline__ u64 pack4bf(f32x4 v) {
  return (u64)f2bf(v[0]) | ((u64)f2bf(v[1]) << 16) |
         ((u64)f2bf(v[2]) << 32) | ((u64)f2bf(v[3]) << 48);
}

// ---------- prologue kernels ----------
__global__ void fc_kernel(const float* __restrict__ x, const float* __restrict__ w,
                          const float* __restrict__ bias, float* __restrict__ z) {
  int idx = blockIdx.x * 256 + threadIdx.x;    // 131072 = 128*1024
  int b = idx >> 10, i = idx & 1023;
  const float* xr = x + b * 256;
  const float* wr = w + i * 256;
  float acc = bias[i];
  #pragma unroll 4
  for (int o = 0; o < 256; ++o) acc += xr[o] * wr[o];
  z[idx] = acc;
}

__global__ void gx0_kernel(const float* __restrict__ z, const float* __restrict__ Wih0,
                           const float* __restrict__ bih, const float* __restrict__ bhh,
                           float* __restrict__ gx0) {
  int idx = blockIdx.x * 256 + threadIdx.x;    // 524288 = 128*4096
  int b = idx >> 12, j = idx & 4095;
  const float* zr = z + b * 1024;
  const float* wr = Wih0 + (size_t)j * 1024;
  float acc = bih[j] + bhh[j];
  #pragma unroll 4
  for (int k = 0; k < 1024; ++k) acc += zr[k] * wr[k];
  gx0[idx] = acc;
}

// ---------- persistent fused 2-layer LSTM, dataflow-synchronized ----------
// 192 blocks x 512 threads, 1 block/CU (LDS-limited: 158 KiB). Roles:
//   role0: layer0 recurrence (h0(t-1) -> h0(t))
//   role1: layer1 input-side (h0(t) -> pa(t), point-to-point to role2 partner)
//   role2: layer1 recurrence + pointwise + out (pa(t), h1(t-1) -> h1(t))
// BASE: R1 (verified best, 6.37ms): wave0-poll -> acquire-fence -> barrier,
// per-producer monotone flags (value = t+1). R6's aggregate counters were
// WRONG (sum>=64t does not imply min>=t: skewed progress admits stale ring
// reads) — per-producer flags restored.
// vs R1, three register-neutral deltas:
// 1. PACKED FLAGS (the R6 intent done correctly): flags at 4B stride, so a
//    64-producer poll touches 4 cache lines (wave-coalesced gather) instead
//    of 64, keeping exact min semantics. Writes are distinct-dword relaxed
//    stores (no RMW, one per block per step) — no same-address contention.
// 2. BACKPRESSURE OFF THE FRONT POLL (from R5, which PASSED correctness):
//    role0's paflag>=t-3 check moves to just before its h-store; role1's
//    partner h1flag>=t-3 check stays at its pa-store. Front poll is pure
//    data dependency.
// 3. role2's out store after publish (no cross-block reader).
// Slot-safety audit (ring depth 4, monotone flags):
//   h0 slot sW written by role0 at t (holds h0(t-4)): role0 peers done
//     reading it at their step t-3 — implied by front wait (h0flag>=t =>
//     peers finished step t-1 >= t-3); role1 done reading at its step t-4
//     iff paflag>=t-3 — checked before the store.
//   h1 slot sW: only role2 reads h1ring; peers implied by front wait.
//   pa slot sW written by role1 at t: partner role2 done reading pa(t-4)
//     iff h1flag[cslice]>=t-3 — checked before the store.
//   role1 reads h0(t) from slot sW: waits h0flag>=t+1 (published after
//     role0's store+drain).
// Deadlock-freedom: role0(t) <- {h0flag>=t, paflag>=t-3}; role1(t) <-
// {h0flag>=t+1, h1flag>=t-3}; role2(t) <- {h1flag>=t, paflag>=t+1}. All
// waits reference publications of strictly earlier or same-step work by a
// role that can complete it first — acyclic by induction on t.
__global__ __launch_bounds__(512, 2)
void lstm_persist(const float* __restrict__ Whh0, const float* __restrict__ Wih1,
                  const float* __restrict__ Whh1, const float* __restrict__ gx0,
                  const float* __restrict__ bih1, const float* __restrict__ bhh1,
                  u16* __restrict__ h0ring, u16* __restrict__ h1ring,
                  float* __restrict__ pabuf, float* __restrict__ out,
                  int* __restrict__ h0flag, int* __restrict__ paflag,
                  int* __restrict__ h1flag) {
  __shared__ __align__(16) u16 wlds[4][2048][8];       // 128 KiB (frag-major W)
  __shared__ __align__(16) float red[4][64][20];       // 20 KiB (padded rows)
  __shared__ __align__(16) float stage[128][20];       // 10 KiB (h staging)

  const int bid = blockIdx.x;
  const int role = bid >> 6;
  const int cslice = bid & 63;
  const int cb = cslice * 16;        // h-col base
  const int tid = threadIdx.x;
  const int w = tid >> 6;            // wave 0..7
  const int lane = tid & 63;
  const int l15 = lane & 15;
  const int q = lane >> 4;
  const int Mg = w & 3;              // M-group: batches Mg*32..+32
  const int kh = w >> 2;             // K-half

  // ---- stage W slice fp32 -> bf16 -> LDS (once) ----
  {
    const float* Wsrc = (role == 0) ? Whh0 : (role == 1) ? Wih1 : Whh1;
    const int r = tid >> 3;          // 0..63: row within slice
    const int g = r >> 4, n = r & 15;
    const int k0 = (tid & 7) * 128;
    const float* src = Wsrc + (((size_t)(g * 1024 + cb + n)) << 10) + k0;
    for (int k = 0; k < 128; k += 4) {
      float4 v = *(const float4*)(src + k);
      ushort4 o;
      o.x = f2bf(v.x); o.y = f2bf(v.y); o.z = f2bf(v.z); o.w = f2bf(v.w);
      const int kk = k0 + k;
      *(ushort4*)&wlds[g][((kk >> 3) << 4) + n][kk & 7] = o;
    }
  }

  // ---- per-thread persistent state ----
  float c_st[2][4];
  #pragma unroll
  for (int mt = 0; mt < 2; ++mt)
    #pragma unroll
    for (int r = 0; r < 4; ++r) c_st[mt][r] = 0.f;

  float gx[2][4][4];                 // role0: gx0 base slice
  float b1[4];                       // role2: bias
  if (role == 0 && w < 4) {
    #pragma unroll
    for (int mt = 0; mt < 2; ++mt)
      #pragma unroll
      for (int g = 0; g < 4; ++g)
        #pragma unroll
        for (int r = 0; r < 4; ++r)
          gx[mt][g][r] = gx0[(size_t)(w * 32 + mt * 16 + q * 4 + r) * 4096 + g * 1024 + cb + l15];
  }
  if (role == 2 && w < 4) {
    #pragma unroll
    for (int g = 0; g < 4; ++g)
      b1[g] = bih1[g * 1024 + cb + l15] + bhh1[g * 1024 + cb + l15];
  }
  __syncthreads();                   // wlds ready

  const size_t HSLOT = (size_t)128 * 1024;   // elems per h ring slot

  for (int t = 0; t < T_SEQ; ++t) {
    const int sA = (t + 3) & 3;      // slot holding h(t-1)
    const int sW = t & 3;            // slot this step writes

    // ---- front wait: wave0 polls its role's 64 packed flags (4 lines) ----
    // role0: h0(t-1) (flag>=t). role1: h0(t) (flag>=t+1). role2: h1(t-1).
    if (w == 0) {
      const int* fl = (role == 2) ? h1flag : h0flag;
      const int thr = (role == 1) ? t + 1 : t;
      bool ok;
      do {
        int f = ld_agent(fl + lane);
        ok = __all(f >= thr);
        if (!ok) __builtin_amdgcn_s_sleep(1);
      } while (!ok);
      __builtin_amdgcn_fence(__ATOMIC_ACQUIRE, "agent");   // L1 inv (CU-wide)
    }
    __syncthreads();

    const u16* A = (role == 0) ? h0ring + (size_t)sA * HSLOT
                 : (role == 1) ? h0ring + (size_t)sW * HSLOT
                               : h1ring + (size_t)sA * HSLOT;

    const int kbase = kh * 512;
    const u16* Ap = A + (((size_t)(Mg * 32 + l15)) << 10) + kbase + q * 8;
    const int cellbase = ((kbase >> 3) + q) * 16 + l15;   // + kk*64

    f32x4 acc0[4] = {{0.f,0.f,0.f,0.f},{0.f,0.f,0.f,0.f},{0.f,0.f,0.f,0.f},{0.f,0.f,0.f,0.f}};
    f32x4 acc1[4] = {{0.f,0.f,0.f,0.f},{0.f,0.f,0.f,0.f},{0.f,0.f,0.f,0.f},{0.f,0.f,0.f,0.f}};

    #pragma unroll
    for (int kk = 0; kk < 16; ++kk) {
      bf16x8 a0 = *(const bf16x8*)(Ap + kk * 32);
      bf16x8 a1 = *(const bf16x8*)(Ap + (16 << 10) + kk * 32);
      #pragma unroll
      for (int g = 0; g < 4; ++g) {
        bf16x8 b = *(const bf16x8*)&wlds[g][cellbase + kk * 64][0];
        acc0[g] = __builtin_amdgcn_mfma_f32_16x16x32_bf16(a0, b, acc0[g], 0, 0, 0);
        acc1[g] = __builtin_amdgcn_mfma_f32_16x16x32_bf16(a1, b, acc1[g], 0, 0, 0);
      }
    }

    // role2: pa(t) wait (1 line, same-addr) + issue u64 loads early; the
    // LDS reduction below hides the load latency (atomic loads: no fence
    // needed — they read the coherence point directly)
    u64 pa64[16];
    const float* pr = pabuf + (size_t)sW * 524288 + (size_t)(cslice * 4 + w) * 2048;
    if (role == 2 && w < 4) {
      while (ld_agent(paflag + cslice) < t + 1) __builtin_amdgcn_s_sleep(1);
      #pragma unroll
      for (int j = 0; j < 8; ++j) {
        pa64[j * 2]     = ld_agent((const u64*)pr + j * 128 + lane * 2);
        pa64[j * 2 + 1] = ld_agent((const u64*)pr + j * 128 + lane * 2 + 1);
      }
    }

    // ---- K-half reduction via LDS (two rounds, 20-word padded rows) ----
    if (w >= 4) {
      #pragma unroll
      for (int g = 0; g < 4; ++g) *(f32x4*)&red[w - 4][lane][g * 4] = acc0[g];
    }
    __syncthreads();
    if (w < 4) {
      #pragma unroll
      for (int g = 0; g < 4; ++g) acc0[g] += *(const f32x4*)&red[w][lane][g * 4];
    }
    __syncthreads();
    if (w >= 4) {
      #pragma unroll
      for (int g = 0; g < 4; ++g) *(f32x4*)&red[w - 4][lane][g * 4] = acc1[g];
    }
    __syncthreads();
    if (w < 4) {
      #pragma unroll
      for (int g = 0; g < 4; ++g) acc1[g] += *(const f32x4*)&red[w][lane][g * 4];

      if (role == 1) {
        // backpressure: partner role2 published h1(t-4) => pabuf slot sW free
        while (ld_agent(h1flag + cslice) < t - 3) __builtin_amdgcn_s_sleep(1);
        float* pw = pabuf + (size_t)sW * 524288 + (size_t)(cslice * 4 + w) * 2048;
        #pragma unroll
        for (int g = 0; g < 4; ++g) {
          st_agent((u64*)pw + g * 128 + lane * 2,           pack2f(acc0[g][0], acc0[g][1]));
          st_agent((u64*)pw + g * 128 + lane * 2 + 1,       pack2f(acc0[g][2], acc0[g][3]));
          st_agent((u64*)pw + (4 + g) * 128 + lane * 2,     pack2f(acc1[g][0], acc1[g][1]));
          st_agent((u64*)pw + (4 + g) * 128 + lane * 2 + 1, pack2f(acc1[g][2], acc1[g][3]));
        }
      } else {
        #pragma unroll
        for (int mt = 0; mt < 2; ++mt) {
          #pragma unroll
          for (int r = 0; r < 4; ++r) {
            float xi, xf, xg, xo;
            f32x4* a = mt ? acc1 : acc0;
            if (role == 0) {
              xi = a[0][r] + gx[mt][0][r];
              xf = a[1][r] + gx[mt][1][r];
              xg = a[2][r] + gx[mt][2][r];
              xo = a[3][r] + gx[mt][3][r];
            } else {
              const int h2 = r >> 1, lo = r & 1;
              auto up = [&](int j) {
                u64 v = pa64[j * 2 + h2];
                return __uint_as_float(lo ? (unsigned)(v >> 32) : (unsigned)v);
              };
              xi = a[0][r] + up(mt * 4 + 0) + b1[0];
              xf = a[1][r] + up(mt * 4 + 1) + b1[1];
              xg = a[2][r] + up(mt * 4 + 2) + b1[2];
              xo = a[3][r] + up(mt * 4 + 3) + b1[3];
            }
            float i_ = sigm_(xi), f_ = sigm_(xf), g_ = tanh_(xg), o_ = sigm_(xo);
            float cn = f_ * c_st[mt][r] + i_ * g_;
            c_st[mt][r] = cn;
            float h = o_ * tanh_(cn);
            stage[w * 32 + mt * 16 + q * 4 + r][l15] = h;   // f32 h to LDS stage
          }
        }
      }
    }

    if (role != 1) {
      __syncthreads();                       // stage[] ready
      if (role == 0) {
        // backpressure: all 64 role1 blocks read h0(t-4) => slot sW free.
        // Packed flags: 4 lines per iteration, 4-step-old => ~1 iteration.
        bool ok;
        do {
          int f = ld_agent(paflag + lane);
          ok = __all(f >= t - 3);
          if (!ok) __builtin_amdgcn_s_sleep(1);
        } while (!ok);
      }
      const int row = tid >> 2, qt = tid & 3;
      f32x4 v = *(const f32x4*)&stage[row][qt * 4];
      u64 pk = pack4bf(v);
      if (role == 0) {
        st_agent((u64*)(h0ring + (size_t)sW * HSLOT + ((size_t)row << 10) + cb) + qt, pk);
      } else {
        st_agent((u64*)(h1ring + (size_t)sW * HSLOT + ((size_t)row << 10) + cb) + qt, pk);
      }
      __syncthreads();                       // per-wave vmcnt drain
      if (tid == 0) {
        if (role == 0) st_agent(h0flag + cslice, t + 1);
        else           st_agent(h1flag + cslice, t + 1);
      }
      if (role == 2) {
        // out has NO cross-block reader: plain cached store, after publish
        *(f32x4*)(out + (size_t)row * ((size_t)T_SEQ * 1024) + (size_t)t * 1024 + cb + qt * 4) = v;
      }
    } else {
      __syncthreads();                       // pa store drain
      if (tid == 0) st_agent(paflag + cslice, t + 1);
    }
  }
}

// ---------- launch ----------
extern "C" void kernel_launch(void* const* d_in, const int* in_sizes, int n_in,
                              void* d_out, int out_size, void* d_ws, size_t ws_size,
                              hipStream_t stream) {
  (void)in_sizes; (void)n_in; (void)out_size; (void)ws_size;
  const float* x    = (const float*)d_in[0];
  const float* fc_w = (const float*)d_in[1];
  const float* fc_b = (const float*)d_in[2];
  const float* Wih0 = (const float*)d_in[3];
  const float* Whh0 = (const float*)d_in[4];
  const float* bih0 = (const float*)d_in[5];
  const float* bhh0 = (const float*)d_in[6];
  const float* Wih1 = (const float*)d_in[7];
  const float* Whh1 = (const float*)d_in[8];
  const float* bih1 = (const float*)d_in[9];
  const float* bhh1 = (const float*)d_in[10];
  float* out = (float*)d_out;

  char* ws = (char*)d_ws;
  size_t off = 0;
  auto alloc = [&](size_t bytes) -> void* {
    void* p = ws + off;
    off += (bytes + 255) & ~(size_t)255;
    return p;
  };
  float* z      = (float*)alloc((size_t)128 * 1024 * 4);
  float* gx0    = (float*)alloc((size_t)128 * 4096 * 4);
  u16*   h0ring = (u16*)alloc((size_t)RSLOT * 128 * 1024 * 2);
  u16*   h1ring = (u16*)alloc((size_t)RSLOT * 128 * 1024 * 2);
  float* pabuf  = (float*)alloc((size_t)RSLOT * 524288 * 4);
  int*   h0flag = (int*)alloc((size_t)64 * 4);
  int*   paflag = (int*)alloc((size_t)64 * 4);
  int*   h1flag = (int*)alloc((size_t)64 * 4);

  hipMemsetAsync(h0ring, 0, (size_t)RSLOT * 128 * 1024 * 2, stream);
  hipMemsetAsync(h1ring, 0, (size_t)RSLOT * 128 * 1024 * 2, stream);
  hipMemsetAsync(h0flag, 0, (size_t)64 * 4, stream);
  hipMemsetAsync(paflag, 0, (size_t)64 * 4, stream);
  hipMemsetAsync(h1flag, 0, (size_t)64 * 4, stream);

  fc_kernel<<<512, 256, 0, stream>>>(x, fc_w, fc_b, z);
  gx0_kernel<<<2048, 256, 0, stream>>>(z, Wih0, bih0, bhh0, gx0);

  lstm_persist<<<NBLK, 512, 0, stream>>>(Whh0, Wih1, Whh1, gx0, bih1, bhh1,
                                         h0ring, h1ring, pabuf, out,
                                         h0flag, paflag, h1flag);
}

// Round 8
// 7080.488 us; speedup vs baseline: 1.8850x; 1.1852x over previous
//
#include <hip/hip_runtime.h>

typedef __attribute__((ext_vector_type(8))) short bf16x8;   // 8 bf16 (4 VGPRs)
typedef __attribute__((ext_vector_type(4))) float f32x4;
typedef unsigned short u16;
typedef unsigned long long u64;

#define T_SEQ 512
#define NBLK  192
#define FPAD  16        // ints per flag slot = one 64B line, ONE writer per line
#define RSLOT 4         // ring depth for h0ring / h1ring / pabuf

__device__ __forceinline__ u16 f2bf(float f) {
  unsigned int u = __float_as_uint(f);
  u += 0x7fffu + ((u >> 16) & 1u);           // RNE
  return (u16)(u >> 16);
}
__device__ __forceinline__ float sigm_(float x) { return 1.f / (1.f + __expf(-x)); }
__device__ __forceinline__ float tanh_(float x) { return 1.f - 2.f / (__expf(2.f * x) + 1.f); }

template <typename T>
__device__ __forceinline__ void st_agent(T* p, T v) {
  __hip_atomic_store(p, v, __ATOMIC_RELAXED, __HIP_MEMORY_SCOPE_AGENT);
}
template <typename T>
__device__ __forceinline__ T ld_agent(const T* p) {
  return __hip_atomic_load(p, __ATOMIC_RELAXED, __HIP_MEMORY_SCOPE_AGENT);
}
// LDS signal ops (workgroup scope: ds_read/ds_write with ordering)
__device__ __forceinline__ void sig_store(int* p, int v) {
  __hip_atomic_store(p, v, __ATOMIC_RELEASE, __HIP_MEMORY_SCOPE_WORKGROUP);
}
__device__ __forceinline__ int sig_load(const int* p) {
  return __hip_atomic_load(p, __ATOMIC_ACQUIRE, __HIP_MEMORY_SCOPE_WORKGROUP);
}
__device__ __forceinline__ u64 pack2f(float a, float b) {
  return (u64)__float_as_uint(a) | ((u64)__float_as_uint(b) << 32);
}
__device__ __forceinline__ u64 pack4bf(f32x4 v) {
  return (u64)f2bf(v[0]) | ((u64)f2bf(v[1]) << 16) |
         ((u64)f2bf(v[2]) << 32) | ((u64)f2bf(v[3]) << 48);
}

// ---------- prologue kernels ----------
__global__ void fc_kernel(const float* __restrict__ x, const float* __restrict__ w,
                          const float* __restrict__ bias, float* __restrict__ z) {
  int idx = blockIdx.x * 256 + threadIdx.x;    // 131072 = 128*1024
  int b = idx >> 10, i = idx & 1023;
  const float* xr = x + b * 256;
  const float* wr = w + i * 256;
  float acc = bias[i];
  #pragma unroll 4
  for (int o = 0; o < 256; ++o) acc += xr[o] * wr[o];
  z[idx] = acc;
}

__global__ void gx0_kernel(const float* __restrict__ z, const float* __restrict__ Wih0,
                           const float* __restrict__ bih, const float* __restrict__ bhh,
                           float* __restrict__ gx0) {
  int idx = blockIdx.x * 256 + threadIdx.x;    // 524288 = 128*4096
  int b = idx >> 12, j = idx & 4095;
  const float* zr = z + b * 1024;
  const float* wr = Wih0 + (size_t)j * 1024;
  float acc = bih[j] + bhh[j];
  #pragma unroll 4
  for (int k = 0; k < 1024; ++k) acc += zr[k] * wr[k];
  gx0[idx] = acc;
}

// ---------- persistent fused 2-layer LSTM, dataflow-synchronized ----------
// 192 blocks x 512 threads, 1 block/CU (LDS-limited). Roles:
//   role0: layer0 recurrence (h0(t-1) -> h0(t))   <- sets the system clock
//   role1: layer1 input-side (h0(t) -> pa(t))
//   role2: layer1 recurrence + pointwise + out
// BASE: R1 (verified best 6.37ms). Flag-mechanics evidence: R5 (8-wave x
// 32-line polling) +64%; R7 (packed 4B flags, 16 writers/line) +22% with
// identical traffic counters => flag lines must be WRITER-EXCLUSIVE and
// SPREAD (R1's FPAD=16 layout), polled by FEW waves.
// vs R1, only the front detect changes (pure-latency edit):
// 1. SPLIT-PHASE DETECT: wave0 polls flags[0..31] (K-half 0 producers,
//    32 lines), acquire-fences, sets LDS sig[0]=t+1; wave4 ditto for
//    flags[32..63] -> sig[1]. Other waves spin on their K-half's sig
//    (ds_read, ~70cy wake, no fabric traffic). No front __syncthreads.
//    Each half starts its A-stream when ITS 32 producers land: halves the
//    straggler set, overlaps the half-streams. Visibility: fence happens
//    after poll and before sig; consumer loads issue after the acquire
//    sig read => after the L1/L2 invalidate (same argument as R1's
//    fence-then-barrier).
// 2. BACKPRESSURE OFF THE POLL: wave1 (role0 only) polls the 64 paflag
//    lines (>= t-3, 4-step stale, ~1 iter) CONCURRENTLY with wave0's data
//    poll, sets sig[2]; the store phase spins on sig[2] (LDS, ~free).
//    Wave0's poll shrinks from R1's 128 lines to 32.
// 3. role2 pa-wait post-MFMA; out store after publish (R5/R7-proven).
// Slot-safety (unchanged from R1): by store time, waves 0-3 observed
// flags[0..31]>=t and waves 4-7 flags[32..63]>=t, joined by the reduce
// barriers => all 64 producers finished step t-1 (so peers consumed slot
// sW at t-3); role1's reads guarded by sig[2] (paflag>=t-3); role1 reads
// h0(t) only after h0flag>=t+1; pa slot guarded by h1flag>=t-3 at store.
// Deadlock-freedom: every wait references strictly-earlier publications
// (induction on t); LDS sigs are set unconditionally by resident pollers.
__global__ __launch_bounds__(512, 2)
void lstm_persist(const float* __restrict__ Whh0, const float* __restrict__ Wih1,
                  const float* __restrict__ Whh1, const float* __restrict__ gx0,
                  const float* __restrict__ bih1, const float* __restrict__ bhh1,
                  u16* __restrict__ h0ring, u16* __restrict__ h1ring,
                  float* __restrict__ pabuf, float* __restrict__ out,
                  int* __restrict__ h0flag, int* __restrict__ paflag,
                  int* __restrict__ h1flag) {
  __shared__ __align__(16) u16 wlds[4][2048][8];       // 128 KiB (frag-major W)
  __shared__ __align__(16) float red[4][64][20];       // 20 KiB (padded rows)
  __shared__ __align__(16) float stage[128][20];       // 10 KiB (h staging)
  __shared__ int sig[4];             // [0]=half0 ready, [1]=half1, [2]=bp

  const int bid = blockIdx.x;
  const int role = bid >> 6;
  const int cslice = bid & 63;
  const int cb = cslice * 16;        // h-col base
  const int tid = threadIdx.x;
  const int w = tid >> 6;            // wave 0..7
  const int lane = tid & 63;
  const int l15 = lane & 15;
  const int q = lane >> 4;
  const int Mg = w & 3;              // M-group: batches Mg*32..+32
  const int kh = w >> 2;             // K-half

  // ---- stage W slice fp32 -> bf16 -> LDS (once) ----
  {
    const float* Wsrc = (role == 0) ? Whh0 : (role == 1) ? Wih1 : Whh1;
    const int r = tid >> 3;          // 0..63: row within slice
    const int g = r >> 4, n = r & 15;
    const int k0 = (tid & 7) * 128;
    const float* src = Wsrc + (((size_t)(g * 1024 + cb + n)) << 10) + k0;
    for (int k = 0; k < 128; k += 4) {
      float4 v = *(const float4*)(src + k);
      ushort4 o;
      o.x = f2bf(v.x); o.y = f2bf(v.y); o.z = f2bf(v.z); o.w = f2bf(v.w);
      const int kk = k0 + k;
      *(ushort4*)&wlds[g][((kk >> 3) << 4) + n][kk & 7] = o;
    }
  }
  if (tid < 4) sig[tid] = 0;

  // ---- per-thread persistent state ----
  float c_st[2][4];
  #pragma unroll
  for (int mt = 0; mt < 2; ++mt)
    #pragma unroll
    for (int r = 0; r < 4; ++r) c_st[mt][r] = 0.f;

  float gx[2][4][4];                 // role0: gx0 base slice
  float b1[4];                       // role2: bias
  if (role == 0 && w < 4) {
    #pragma unroll
    for (int mt = 0; mt < 2; ++mt)
      #pragma unroll
      for (int g = 0; g < 4; ++g)
        #pragma unroll
        for (int r = 0; r < 4; ++r)
          gx[mt][g][r] = gx0[(size_t)(w * 32 + mt * 16 + q * 4 + r) * 4096 + g * 1024 + cb + l15];
  }
  if (role == 2 && w < 4) {
    #pragma unroll
    for (int g = 0; g < 4; ++g)
      b1[g] = bih1[g * 1024 + cb + l15] + bhh1[g * 1024 + cb + l15];
  }
  __syncthreads();                   // wlds + sig init ready

  const size_t HSLOT = (size_t)128 * 1024;   // elems per h ring slot

  for (int t = 0; t < T_SEQ; ++t) {
    const int sA = (t + 3) & 3;      // slot holding h(t-1)
    const int sW = t & 3;            // slot this step writes

    // ---- split-phase front detect ----
    if (role == 0 && w == 1) {
      // backpressure poller (concurrent with wave0's data poll):
      // all 64 role1 blocks read h0(t-4) iff paflag >= t-3. 64 exclusive
      // lines, 4-step stale => ~1 iteration.
      bool ok;
      do {
        int f = ld_agent(paflag + lane * FPAD);
        ok = __all(f >= t - 3);
        if (!ok) __builtin_amdgcn_s_sleep(1);
      } while (!ok);
      sig_store(&sig[2], t + 1);
    }
    if ((w & 3) == 0) {
      // data poller for this K-half: wave0 -> flags[0..31], wave4 -> [32..63]
      const int half = w >> 2;
      const int* fl = (role == 2) ? h1flag : h0flag;
      const int thr = (role == 1) ? t + 1 : t;
      const int pl = half * 32 + (lane & 31);
      bool ok;
      do {
        int f = ld_agent(fl + pl * FPAD);
        ok = __all(f >= thr);
        if (!ok) __builtin_amdgcn_s_sleep(1);
      } while (!ok);
      __builtin_amdgcn_fence(__ATOMIC_ACQUIRE, "agent");   // L1/L2 inv BEFORE sig
      sig_store(&sig[half], t + 1);
    } else {
      while (sig_load(&sig[kh]) < t + 1) { /* LDS spin, ~70cy wake */ }
    }

    const u16* A = (role == 0) ? h0ring + (size_t)sA * HSLOT
                 : (role == 1) ? h0ring + (size_t)sW * HSLOT
                               : h1ring + (size_t)sA * HSLOT;

    const int kbase = kh * 512;
    const u16* Ap = A + (((size_t)(Mg * 32 + l15)) << 10) + kbase + q * 8;
    const int cellbase = ((kbase >> 3) + q) * 16 + l15;   // + kk*64

    f32x4 acc0[4] = {{0.f,0.f,0.f,0.f},{0.f,0.f,0.f,0.f},{0.f,0.f,0.f,0.f},{0.f,0.f,0.f,0.f}};
    f32x4 acc1[4] = {{0.f,0.f,0.f,0.f},{0.f,0.f,0.f,0.f},{0.f,0.f,0.f,0.f},{0.f,0.f,0.f,0.f}};

    #pragma unroll
    for (int kk = 0; kk < 16; ++kk) {
      bf16x8 a0 = *(const bf16x8*)(Ap + kk * 32);
      bf16x8 a1 = *(const bf16x8*)(Ap + (16 << 10) + kk * 32);
      #pragma unroll
      for (int g = 0; g < 4; ++g) {
        bf16x8 b = *(const bf16x8*)&wlds[g][cellbase + kk * 64][0];
        acc0[g] = __builtin_amdgcn_mfma_f32_16x16x32_bf16(a0, b, acc0[g], 0, 0, 0);
        acc1[g] = __builtin_amdgcn_mfma_f32_16x16x32_bf16(a1, b, acc1[g], 0, 0, 0);
      }
    }

    // role2: pa(t) wait (1 exclusive line, same-addr) + issue u64 atomic
    // loads early; the LDS reduction hides the load latency.
    u64 pa64[16];
    const float* pr = pabuf + (size_t)sW * 524288 + (size_t)(cslice * 4 + w) * 2048;
    if (role == 2 && w < 4) {
      while (ld_agent(paflag + cslice * FPAD) < t + 1) __builtin_amdgcn_s_sleep(1);
      #pragma unroll
      for (int j = 0; j < 8; ++j) {
        pa64[j * 2]     = ld_agent((const u64*)pr + j * 128 + lane * 2);
        pa64[j * 2 + 1] = ld_agent((const u64*)pr + j * 128 + lane * 2 + 1);
      }
    }

    // ---- K-half reduction via LDS (two rounds, 20-word padded rows) ----
    if (w >= 4) {
      #pragma unroll
      for (int g = 0; g < 4; ++g) *(f32x4*)&red[w - 4][lane][g * 4] = acc0[g];
    }
    __syncthreads();
    if (w < 4) {
      #pragma unroll
      for (int g = 0; g < 4; ++g) acc0[g] += *(const f32x4*)&red[w][lane][g * 4];
    }
    __syncthreads();
    if (w >= 4) {
      #pragma unroll
      for (int g = 0; g < 4; ++g) *(f32x4*)&red[w - 4][lane][g * 4] = acc1[g];
    }
    __syncthreads();
    if (w < 4) {
      #pragma unroll
      for (int g = 0; g < 4; ++g) acc1[g] += *(const f32x4*)&red[w][lane][g * 4];

      if (role == 1) {
        // backpressure: partner role2 published h1(t-4) => pabuf slot sW free
        while (ld_agent(h1flag + cslice * FPAD) < t - 3) __builtin_amdgcn_s_sleep(1);
        float* pw = pabuf + (size_t)sW * 524288 + (size_t)(cslice * 4 + w) * 2048;
        #pragma unroll
        for (int g = 0; g < 4; ++g) {
          st_agent((u64*)pw + g * 128 + lane * 2,           pack2f(acc0[g][0], acc0[g][1]));
          st_agent((u64*)pw + g * 128 + lane * 2 + 1,       pack2f(acc0[g][2], acc0[g][3]));
          st_agent((u64*)pw + (4 + g) * 128 + lane * 2,     pack2f(acc1[g][0], acc1[g][1]));
          st_agent((u64*)pw + (4 + g) * 128 + lane * 2 + 1, pack2f(acc1[g][2], acc1[g][3]));
        }
      } else {
        #pragma unroll
        for (int mt = 0; mt < 2; ++mt) {
          #pragma unroll
          for (int r = 0; r < 4; ++r) {
            float xi, xf, xg, xo;
            f32x4* a = mt ? acc1 : acc0;
            if (role == 0) {
              xi = a[0][r] + gx[mt][0][r];
              xf = a[1][r] + gx[mt][1][r];
              xg = a[2][r] + gx[mt][2][r];
              xo = a[3][r] + gx[mt][3][r];
            } else {
              const int h2 = r >> 1, lo = r & 1;
              auto up = [&](int j) {
                u64 v = pa64[j * 2 + h2];
                return __uint_as_float(lo ? (unsigned)(v >> 32) : (unsigned)v);
              };
              xi = a[0][r] + up(mt * 4 + 0) + b1[0];
              xf = a[1][r] + up(mt * 4 + 1) + b1[1];
              xg = a[2][r] + up(mt * 4 + 2) + b1[2];
              xo = a[3][r] + up(mt * 4 + 3) + b1[3];
            }
            float i_ = sigm_(xi), f_ = sigm_(xf), g_ = tanh_(xg), o_ = sigm_(xo);
            float cn = f_ * c_st[mt][r] + i_ * g_;
            c_st[mt][r] = cn;
            float h = o_ * tanh_(cn);
            stage[w * 32 + mt * 16 + q * 4 + r][l15] = h;   // f32 h to LDS stage
          }
        }
      }
    }

    if (role != 1) {
      __syncthreads();                       // stage[] ready
      if (role == 0) {
        // backpressure gate: wave1 already verified paflag>=t-3 and set
        // sig[2]=t+1 during the front phase. LDS spin, ~always immediate.
        while (sig_load(&sig[2]) < t + 1) { }
      }
      const int row = tid >> 2, qt = tid & 3;
      f32x4 v = *(const f32x4*)&stage[row][qt * 4];
      u64 pk = pack4bf(v);
      if (role == 0) {
        st_agent((u64*)(h0ring + (size_t)sW * HSLOT + ((size_t)row << 10) + cb) + qt, pk);
      } else {
        st_agent((u64*)(h1ring + (size_t)sW * HSLOT + ((size_t)row << 10) + cb) + qt, pk);
      }
      __syncthreads();                       // per-wave vmcnt drain
      if (tid == 0) {
        if (role == 0) st_agent(h0flag + cslice * FPAD, t + 1);
        else           st_agent(h1flag + cslice * FPAD, t + 1);
      }
      if (role == 2) {
        // out has NO cross-block reader: plain cached store, after publish
        *(f32x4*)(out + (size_t)row * ((size_t)T_SEQ * 1024) + (size_t)t * 1024 + cb + qt * 4) = v;
      }
    } else {
      __syncthreads();                       // pa store drain
      if (tid == 0) st_agent(paflag + cslice * FPAD, t + 1);
    }
  }
}

// ---------- launch ----------
extern "C" void kernel_launch(void* const* d_in, const int* in_sizes, int n_in,
                              void* d_out, int out_size, void* d_ws, size_t ws_size,
                              hipStream_t stream) {
  (void)in_sizes; (void)n_in; (void)out_size; (void)ws_size;
  const float* x    = (const float*)d_in[0];
  const float* fc_w = (const float*)d_in[1];
  const float* fc_b = (const float*)d_in[2];
  const float* Wih0 = (const float*)d_in[3];
  const float* Whh0 = (const float*)d_in[4];
  const float* bih0 = (const float*)d_in[5];
  const float* bhh0 = (const float*)d_in[6];
  const float* Wih1 = (const float*)d_in[7];
  const float* Whh1 = (const float*)d_in[8];
  const float* bih1 = (const float*)d_in[9];
  const float* bhh1 = (const float*)d_in[10];
  float* out = (float*)d_out;

  char* ws = (char*)d_ws;
  size_t off = 0;
  auto alloc = [&](size_t bytes) -> void* {
    void* p = ws + off;
    off += (bytes + 255) & ~(size_t)255;
    return p;
  };
  float* z      = (float*)alloc((size_t)128 * 1024 * 4);
  float* gx0    = (float*)alloc((size_t)128 * 4096 * 4);
  u16*   h0ring = (u16*)alloc((size_t)RSLOT * 128 * 1024 * 2);
  u16*   h1ring = (u16*)alloc((size_t)RSLOT * 128 * 1024 * 2);
  float* pabuf  = (float*)alloc((size_t)RSLOT * 524288 * 4);
  int*   h0flag = (int*)alloc((size_t)64 * FPAD * 4);
  int*   paflag = (int*)alloc((size_t)64 * FPAD * 4);
  int*   h1flag = (int*)alloc((size_t)64 * FPAD * 4);

  hipMemsetAsync(h0ring, 0, (size_t)RSLOT * 128 * 1024 * 2, stream);
  hipMemsetAsync(h1ring, 0, (size_t)RSLOT * 128 * 1024 * 2, stream);
  hipMemsetAsync(h0flag, 0, (size_t)64 * FPAD * 4, stream);
  hipMemsetAsync(paflag, 0, (size_t)64 * FPAD * 4, stream);
  hipMemsetAsync(h1flag, 0, (size_t)64 * FPAD * 4, stream);

  fc_kernel<<<512, 256, 0, stream>>>(x, fc_w, fc_b, z);
  gx0_kernel<<<2048, 256, 0, stream>>>(z, Wih0, bih0, bhh0, gx0);

  lstm_persist<<<NBLK, 512, 0, stream>>>(Whh0, Wih1, Whh1, gx0, bih1, bhh1,
                                         h0ring, h1ring, pabuf, out,
                                         h0flag, paflag, h1flag);
}